// Round 15
// baseline (239.442 us; speedup 1.0000x reference)
//
#include <hip/hip_runtime.h>

typedef unsigned short u16;
typedef unsigned int   u32;
typedef __bf16  bf16x8 __attribute__((ext_vector_type(8)));
typedef float   f32x4  __attribute__((ext_vector_type(4)));
typedef u16     u16x8  __attribute__((ext_vector_type(8)));
typedef u16     u16x4  __attribute__((ext_vector_type(4)));
typedef u32     u32x2  __attribute__((ext_vector_type(2)));

#define MFMA16(a, b, c) __builtin_amdgcn_mfma_f32_16x16x32_bf16((a), (b), (c), 0, 0, 0)

// async global->LDS, 16B per lane (dest must be wave-uniform base + lane*16)
#define GLOAD16(gsrc, ldst)                                                     \
  __builtin_amdgcn_global_load_lds(                                             \
      (__attribute__((address_space(1))) void*)(gsrc),                          \
      (__attribute__((address_space(3))) void*)(ldst), 16, 0, 0)

__device__ __forceinline__ u16 f2bf(float f) {
  union { float f; unsigned u; } v; v.f = f;
  unsigned r = v.u + 0x7FFFu + ((v.u >> 16) & 1u);   // RNE
  return (u16)(r >> 16);
}
__device__ __forceinline__ float bf2f(u16 u) {
  union { unsigned u; float f; } v; v.u = ((unsigned)u) << 16; return v.f;
}
// pack two f32 -> two bf16 in one VALU op (lo -> bits 0..15)
__device__ __forceinline__ u32 cvtpk(float a, float b) {
  u32 r;
  asm("v_cvt_pk_bf16_f32 %0, %1, %2" : "=v"(r) : "v"(a), "v"(b));
  return r;
}

// cross-phase handshake (re-zeroed every launch by prep, stream-ordered)
__device__ int g_cnt[64];   // per (b,qg) band: heads completed (target 12)
__device__ int g_qctr;      // bt64 tile queue head

// --------------------------------------------------------------- fused prep --
// One kernel, three jobs by blockIdx range:
//   [0,3072)        : x fp32 -> xb bf16 (float4/u16x4 vectorized)
//   [3072,4800)     : Wqkv [768][2304] -> wqkvT [2304][768] bf16
//   [4800,5376)     : Wo   [768][768]  -> woT   [768][768]  bf16
__global__ __launch_bounds__(256) void prep(const float* __restrict__ x,
                                            u16* __restrict__ xb,
                                            const float* __restrict__ Wqkv,
                                            u16* __restrict__ wqkvT,
                                            const float* __restrict__ Wo,
                                            u16* __restrict__ woT) {
  __shared__ u16 tile[32][33];
  const int bx = blockIdx.x;
  if (bx == 0) {                                // zero handshake state
    if (threadIdx.x < 64) g_cnt[threadIdx.x] = 0;
    if (threadIdx.x == 64) g_qctr = 0;
  }
  if (bx < 3072) {                              // ---- f2bf on x
    int i = bx * 256 + threadIdx.x;             // n4 = 786432 = 3072*256
    const float4 v = reinterpret_cast<const float4*>(x)[i];
    u16x4 o; o.x = f2bf(v.x); o.y = f2bf(v.y); o.z = f2bf(v.z); o.w = f2bf(v.w);
    reinterpret_cast<u16x4*>(xb)[i] = o;
    return;
  }
  const float* in; u16* out; int R, C, c0, r0;
  if (bx < 4800) {                              // ---- transpose Wqkv
    const int i = bx - 3072;                    // 72 x 24 tiles
    in = Wqkv; out = wqkvT; R = 768; C = 2304;
    c0 = (i % 72) * 32; r0 = (i / 72) * 32;
  } else {                                      // ---- transpose Wo
    const int i = bx - 4800;                    // 24 x 24 tiles
    in = Wo; out = woT; R = 768; C = 768;
    c0 = (i % 24) * 32; r0 = (i / 24) * 32;
  }
  int tx = threadIdx.x & 31, ty = threadIdx.x >> 5;   // 8 rows per pass
  #pragma unroll
  for (int i = ty; i < 32; i += 8)
    tile[i][tx] = f2bf(in[(size_t)(r0 + i) * C + (c0 + tx)]);
  __syncthreads();
  #pragma unroll
  for (int i = ty; i < 32; i += 8)
    out[(size_t)(c0 + i) * R + (r0 + tx)] = tile[tx][i];
}

// ------------------------------------------------- fused QKV GEMM + RoPE ----
// A = xb [4096][768] bf16, Bt = wqkvT [2304][768] bf16.
// blockIdx.z = type (0=Q,1=K,2=V). 128x128 tile, BK=64, single-buffered
// (32KB LDS -> 5 blocks/CU; R10 dbuf regression = m132). XOR swizzle:
// measured zero bank conflicts. Verified best config (85.7us pipeline).
__global__ __launch_bounds__(256) void gemm_qkv(const u16* __restrict__ A,
                                                const u16* __restrict__ Bt,
                                                u16* __restrict__ q,
                                                u16* __restrict__ k,
                                                u16* __restrict__ vt,
                                                const int* __restrict__ seq_len) {
  __shared__ u16 As[128 * 64];
  __shared__ u16 Bs[128 * 64];
  const int tid = threadIdx.x;
  const int lane = tid & 63;
  const int w  = tid >> 6;
  const int wr = w >> 1, wc = w & 1;           // 2x2 waves, each 64x64 out
  const int lo = lane & 15, g = lane >> 4;
  const int type = blockIdx.z;                 // 0=q 1=k 2=v
  const int bxl  = blockIdx.x;                 // 0..5
  const int m0 = blockIdx.y * 128;
  const int n0 = type * 768 + bxl * 128;
  const int K = 768;

  f32x4 acc[4][4] = {};
  for (int kt = 0; kt < 12; ++kt) {
    __syncthreads();
    #pragma unroll
    for (int i = 0; i < 4; ++i) {
      int idx = i * 256 + tid;                 // 1024 chunks of 16B per matrix
      int row = idx >> 3, sc = idx & 7;
      const int col = ((sc ^ (row & 7)) * 8);  // pre-swizzled source
      GLOAD16(&A [(size_t)(m0 + row) * K + kt * 64 + col], &As[idx * 8]);
      GLOAD16(&Bt[(size_t)(n0 + row) * K + kt * 64 + col], &Bs[idx * 8]);
    }
    __syncthreads();

    #pragma unroll
    for (int kk = 0; kk < 2; ++kk) {
      bf16x8 af[4], bfr[4];
      #pragma unroll
      for (int mi = 0; mi < 4; ++mi)
        af[mi] = *(const bf16x8*)&As[(wr * 64 + mi * 16 + lo) * 64 +
                                     (((kk * 4 + g) ^ (lo & 7)) * 8)];
      #pragma unroll
      for (int ni = 0; ni < 4; ++ni)
        bfr[ni] = *(const bf16x8*)&Bs[(wc * 64 + ni * 16 + lo) * 64 +
                                      (((kk * 4 + g) ^ (lo & 7)) * 8)];
      #pragma unroll
      for (int mi = 0; mi < 4; ++mi)
        #pragma unroll
        for (int ni = 0; ni < 4; ++ni)
          acc[mi][ni] = MFMA16(af[mi], bfr[ni], acc[mi][ni]);
    }
  }

  // epilogue: D layout col=lane&15 (within 16), row=(lane>>4)*4+r
  const int hh = bxl * 2 + wc;                 // head 0..11
  const int bb = m0 >> 11;                     // batch (128 | 2048)
  const int tbase = (m0 & 2047) + wr * 64;     // local t base for this wave

  if (type == 2) {                             // V -> vt [bh][d][t]
    #pragma unroll
    for (int ni = 0; ni < 4; ++ni) {
      const int d = ni * 16 + lo;
      u16* dst = &vt[(((size_t)bb * 12 + hh) * 64 + d) * 2048];
      #pragma unroll
      for (int mi = 0; mi < 4; ++mi) {
        const int tl = tbase + mi * 16 + g * 4;
        u16x4 o;
        #pragma unroll
        for (int r = 0; r < 4; ++r) o[r] = f2bf(acc[mi][ni][r]);
        *(u16x4*)&dst[tl] = o;
      }
    }
  } else {                                     // Q/K -> RoPE -> [bh][t][64]
    const float QS = 0.18033688011112042f;     // 0.125 * log2(e)
    const int off = seq_len[0];
    const float invf0 = __expf(-(float)lo        * 0.28782313662425572f);
    const float invf1 = __expf(-(float)(lo + 16) * 0.28782313662425572f);
    u16* base = &((type == 0) ? q : k)[((size_t)bb * 12 + hh) * 2048 * 64];
    #pragma unroll
    for (int mi = 0; mi < 4; ++mi)
      #pragma unroll
      for (int r = 0; r < 4; ++r) {
        const int tl = tbase + mi * 16 + g * 4 + r;
        const float pos = (float)(tl + off);
        float s0, c0, s1, c1;
        __sincosf(pos * invf0, &s0, &c0);
        __sincosf(pos * invf1, &s1, &c1);
        const float x1a = acc[mi][0][r], x2a = acc[mi][2][r];
        const float x1b = acc[mi][1][r], x2b = acc[mi][3][r];
        float o0 = x1a * c0 - x2a * s0, o2 = x2a * c0 + x1a * s0;
        float o1 = x1b * c1 - x2b * s1, o3 = x2b * c1 + x1b * s1;
        if (type == 0) { o0 *= QS; o1 *= QS; o2 *= QS; o3 *= QS; }
        u16* p = &base[(size_t)tl * 64];
        p[lo]      = f2bf(o0);
        p[lo + 16] = f2bf(o1);
        p[lo + 32] = f2bf(o2);
        p[lo + 48] = f2bf(o3);
      }
  }
}

// ------------------------------------------- fused flash attn + out GEMM ----
// R15: persistent 768-block kernel. Phase 1 = verified fattn v14 (unchanged
// math/layout). Phase 2 = verified gemm_bt64 dbuf tile, pulled from an atomic
// queue with per-band readiness counters, so bt64 runs on the CUs that the
// light fattn blocks vacate while the 32-step heavy blocks are still going.
// Deadlock-free under ANY dispatch order: producers (phase 1) never wait, and
// grid 768 = exactly 3 blocks/CU at 48KB LDS so all producers co-resident.
// Handshake: producer O-writes -> __threadfence -> atomicAdd(g_cnt[band]);
// consumer spins until g_cnt[band]==12 (all heads), fences, then stages.
// LDS overlaid: phase1 Ks/Vs/Ps = 42KB, phase2 As/Bs dbuf = 48KB (union).
__global__ __launch_bounds__(256, 3) void attn_out(const u16* __restrict__ Q,
                                                   const u16* __restrict__ K,
                                                   const u16* __restrict__ Vt,
                                                   u16* __restrict__ O,
                                                   const u16* __restrict__ woT,
                                                   float* __restrict__ Cout) {
  __shared__ __align__(16) u16 smem[24576];     // 49152 B (max of both phases)
  __shared__ int sJ;
  const int tid = threadIdx.x;
  const int w = tid >> 6, l = tid & 63;
  const int lo = l & 15, g = l >> 4;

  // ---------------- phase 1: flash attention (verified v14) ----------------
  {
    u16 (*Ks)[4096] = (u16(*)[4096])(smem);           // 16KB
    u16 (*Vs)[4096] = (u16(*)[4096])(smem + 8192);    // 16KB
    u32* Psb = (u32*)(smem + 16384);                  // 9216B (4 x 16 x 36)
    u32* myP = Psb + w * 576 + lo * 36;               // lane's own q-row

    // staging indices: 512 x 16B chunks per matrix, 2 per thread
    const int i0 = tid, i1 = 256 + tid;
    const int r0 = i0 >> 3, s0 = i0 & 7;
    const int r1 = i1 >> 3, s1 = i1 & 7;
    const size_t kg0 = (size_t)r0 * 64   + ((s0 ^ (r0 & 7)) * 8);
    const size_t vg0 = (size_t)r0 * 2048 + ((s0 ^ (r0 & 7)) * 8);
    const size_t kg1 = (size_t)r1 * 64   + ((s1 ^ (r1 & 7)) * 8);
    const size_t vg1 = (size_t)r1 * 2048 + ((s1 ^ (r1 & 7)) * 8);

    // static block -> job-rank permutation (768 jobs, rank 0 = heaviest)
    const int bx = blockIdx.x;
    int rk;
    if (bx < 256)      rk = bx;                 // heavy: nkv 32..22
    else if (bx < 512) rk = 1023 - bx;          // light: nkv 1..10
    else { const int c = bx - 512;              // middle: nkv 11..21
           rk = (c & 1) ? 511 - (c >> 1) : 256 + (c >> 1); }

    const int qg  = 31 - rk / 24;
    const int bh  = (rk & 7) * 3 + ((rk >> 3) % 3);
    const int nkv = qg + 1;
    const int q0  = qg * 64 + w * 16;           // wave's first q row
    const u16* Qb = Q  + (size_t)bh * 2048 * 64;
    const u16* Kb = K  + (size_t)bh * 2048 * 64;
    const u16* Vb = Vt + (size_t)bh * 64 * 2048;
    const int b = bh / 12, h = bh - b * 12;

    const bf16x8 qf0 = *(const bf16x8*)&Qb[(size_t)(q0 + lo) * 64 + g * 8];
    const bf16x8 qf1 = *(const bf16x8*)&Qb[(size_t)(q0 + lo) * 64 + 32 + g * 8];

    f32x4 acc[4] = {};                          // acc[dt][r]: O^T[16dt+4g+r][q0+lo]
    float m_run = -1e30f, l_run = 0.f;          // l_run is LANE-PARTIAL

    auto step = [&](int cur, bool diag) __attribute__((always_inline)) {
      bf16x8 kf[8];
      #pragma unroll
      for (int ct = 0; ct < 4; ++ct) {
        const int base = (ct * 16 + lo) * 64;
        kf[ct * 2]     = *(const bf16x8*)&Ks[cur][base + ((g ^ (lo & 7)) * 8)];
        kf[ct * 2 + 1] = *(const bf16x8*)&Ks[cur][base + (((4 + g) ^ (lo & 7)) * 8)];
      }
      bf16x8 vf[8];                             // early: overlaps softmax
      #pragma unroll
      for (int ss = 0; ss < 2; ++ss)
        #pragma unroll
        for (int dt = 0; dt < 4; ++dt) {
          const int row = dt * 16 + lo;
          vf[ss * 4 + dt] = *(const bf16x8*)&Vs[cur][row * 64 + (((ss * 4 + g) ^ (lo & 7)) * 8)];
        }

      f32x4 s[4];
      __builtin_amdgcn_s_setprio(1);
      #pragma unroll
      for (int ct = 0; ct < 4; ++ct) {
        f32x4 t = {};
        t = MFMA16(kf[ct * 2], qf0, t);
        t = MFMA16(kf[ct * 2 + 1], qf1, t);
        s[ct] = t;
      }
      __builtin_amdgcn_s_setprio(0);

      if (diag) {                               // ct<w full, ct==w tri, ct>w off
        #pragma unroll
        for (int ct = 0; ct < 4; ++ct) {
          if (ct > w) s[ct] = (f32x4){-1e30f, -1e30f, -1e30f, -1e30f};
          else if (ct == w) {
            #pragma unroll
            for (int r = 0; r < 4; ++r)
              if (g * 4 + r > lo) s[ct][r] = -1e30f;
          }
        }
      }

      float pm = s[0][0];                       // lane-local max only
      #pragma unroll
      for (int ct = 0; ct < 4; ++ct)
        #pragma unroll
        for (int r = 0; r < 4; ++r) pm = fmaxf(pm, s[ct][r]);
      if (!__all(pm - m_run <= 12.0f)) {        // rare: row max + rescale
        float pr = fmaxf(pm, __shfl_xor(pm, 16));
        pr = fmaxf(pr, __shfl_xor(pr, 32));
        const float mnew = fmaxf(m_run, pr);
        const float corr = exp2f(m_run - mnew);
        l_run *= corr;
        #pragma unroll
        for (int dt = 0; dt < 4; ++dt)
          #pragma unroll
          for (int r = 0; r < 4; ++r) acc[dt][r] *= corr;
        m_run = mnew;
      }
      float p[4][4];
      float rs = 0.f;
      #pragma unroll
      for (int ct = 0; ct < 4; ++ct)
        #pragma unroll
        for (int r = 0; r < 4; ++r) {
          float pv = exp2f(s[ct][r] - m_run);   // scores already in log2 domain
          p[ct][r] = pv; rs += pv;
        }
      l_run += rs;

      #pragma unroll
      for (int ct = 0; ct < 4; ++ct) {          // P -> per-wave LDS (cvt_pk)
        u32x2 pk;
        pk.x = cvtpk(p[ct][0], p[ct][1]);
        pk.y = cvtpk(p[ct][2], p[ct][3]);
        *(u32x2*)&myP[ct * 8 + g * 2] = pk;
      }

      __builtin_amdgcn_s_setprio(1);
      #pragma unroll
      for (int ss = 0; ss < 2; ++ss) {
        const bf16x8 pf = *(const bf16x8*)&myP[ss * 16 + g * 4];
        #pragma unroll
        for (int dt = 0; dt < 4; ++dt)
          acc[dt] = MFMA16(vf[ss * 4 + dt], pf, acc[dt]);
      }
      __builtin_amdgcn_s_setprio(0);
    };

    // incremental staging pointers (tile stride: K 64*64, Vt 64 u16)
    const u16 *kp0 = Kb + kg0, *kp1 = Kb + kg1;
    const u16 *vp0 = Vb + vg0, *vp1 = Vb + vg1;

    GLOAD16(kp0, &Ks[0][i0 * 8]);
    GLOAD16(kp1, &Ks[0][i1 * 8]);
    GLOAD16(vp0, &Vs[0][i0 * 8]);
    GLOAD16(vp1, &Vs[0][i1 * 8]);
    __syncthreads();

    for (int it = 0; it < nkv - 1; ++it) {      // maskless main loop
      const int cur = it & 1;
      kp0 += 4096; kp1 += 4096; vp0 += 64; vp1 += 64;
      GLOAD16(kp0, &Ks[cur ^ 1][i0 * 8]);
      GLOAD16(kp1, &Ks[cur ^ 1][i1 * 8]);
      GLOAD16(vp0, &Vs[cur ^ 1][i0 * 8]);
      GLOAD16(vp1, &Vs[cur ^ 1][i1 * 8]);
      step(cur, false);
      __syncthreads();
    }
    step((nkv - 1) & 1, true);                  // single peeled diag step

    float lt = l_run;                           // row reduce, once
    lt += __shfl_xor(lt, 16);
    lt += __shfl_xor(lt, 32);
    const float inv = 1.f / lt;
    #pragma unroll
    for (int dt = 0; dt < 4; ++dt) {
      u16x4 o;
      #pragma unroll
      for (int r = 0; r < 4; ++r) o[r] = f2bf(acc[dt][r] * inv);
      *(u16x4*)&O[(size_t)(b * 2048 + q0 + lo) * 768 + h * 64 + dt * 16 + g * 4] = o;
    }

    // publish: this job completed head h of band (b,qg)
    __threadfence();
    __syncthreads();
    if (tid == 0) atomicAdd(&g_cnt[b * 32 + qg], 1);
  }

  // ---------------- phase 2: out GEMM tiles from readiness queue ----------
  {
    u16 (*As2)[4096] = (u16(*)[4096])(smem);          // 2 x 64x64  (16KB)
    u16 (*Bs2)[8192] = (u16(*)[8192])(smem + 8192);   // 2 x 128x64 (32KB)
    const int wr = w >> 1, wc = w & 1;          // 2x2 waves, each 32x64 out
    const int N = 768, Kd = 768;

    for (;;) {
      __syncthreads();                          // smem safe to overwrite
      if (tid == 0) sJ = atomicAdd(&g_qctr, 1);
      __syncthreads();
      const int j = sJ;
      if (j >= 384) break;
      // queue ordered by readiness: qg ascending (light bands finish first)
      const int qgb = j / 12, rb = j % 12, b2 = rb / 6, n = rb % 6;
      const int band = b2 * 32 + qgb;
      const int m0 = band * 64, n0 = n * 128;

      if (tid == 0) {                           // wait all 12 heads of band
        while (atomicAdd(&g_cnt[band], 0) < 12) __builtin_amdgcn_s_sleep(2);
      }
      __syncthreads();
      __threadfence();                          // acquire: aout rows visible

      auto stage = [&](int bu, int kt_) __attribute__((always_inline)) {
        #pragma unroll
        for (int i = 0; i < 2; ++i) {           // A: 512 chunks, 2/thread
          int idx = i * 256 + tid;
          int row = idx >> 3, sc = idx & 7;
          GLOAD16(&O[(size_t)(m0 + row) * Kd + kt_ * 64 + ((sc ^ (row & 7)) * 8)],
                  &As2[bu][idx * 8]);
        }
        #pragma unroll
        for (int i = 0; i < 4; ++i) {           // B: 1024 chunks, 4/thread
          int idx = i * 256 + tid;
          int row = idx >> 3, sc = idx & 7;
          GLOAD16(&woT[(size_t)(n0 + row) * Kd + kt_ * 64 + ((sc ^ (row & 7)) * 8)],
                  &Bs2[bu][idx * 8]);
        }
      };

      f32x4 acc2[2][4] = {};
      stage(0, 0);
      __syncthreads();
      for (int kt = 0; kt < 12; ++kt) {
        const int cur = kt & 1;
        if (kt + 1 < 12) stage(cur ^ 1, kt + 1);  // prefetch next tile

        #pragma unroll
        for (int kk = 0; kk < 2; ++kk) {
          bf16x8 af[2], bfr[4];
          #pragma unroll
          for (int mi = 0; mi < 2; ++mi)
            af[mi] = *(const bf16x8*)&As2[cur][(wr * 32 + mi * 16 + lo) * 64 +
                                               (((kk * 4 + g) ^ (lo & 7)) * 8)];
          #pragma unroll
          for (int ni = 0; ni < 4; ++ni)
            bfr[ni] = *(const bf16x8*)&Bs2[cur][(wc * 64 + ni * 16 + lo) * 64 +
                                                (((kk * 4 + g) ^ (lo & 7)) * 8)];
          #pragma unroll
          for (int mi = 0; mi < 2; ++mi)
            #pragma unroll
            for (int ni = 0; ni < 4; ++ni)
              acc2[mi][ni] = MFMA16(af[mi], bfr[ni], acc2[mi][ni]);
        }
        __syncthreads();                        // drains prefetch after compute
      }

      #pragma unroll
      for (int mi = 0; mi < 2; ++mi)
        #pragma unroll
        for (int ni = 0; ni < 4; ++ni)
          #pragma unroll
          for (int r = 0; r < 4; ++r) {
            int row = m0 + wr * 32 + mi * 16 + g * 4 + r;
            int col = n0 + wc * 64 + ni * 16 + lo;
            Cout[(size_t)row * N + col] = acc2[mi][ni][r];
          }
    }
  }
}

// ---------------------------------------------------------------- launch ----
extern "C" void kernel_launch(void* const* d_in, const int* in_sizes, int n_in,
                              void* d_out, int out_size, void* d_ws, size_t ws_size,
                              hipStream_t stream) {
  const float* x    = (const float*)d_in[0];   // [2,2048,768]
  const float* Wqkv = (const float*)d_in[1];   // [768,2304]
  const float* Wo   = (const float*)d_in[2];   // [768,768]
  const int*   sl   = (const int*)d_in[3];

  u16* ws    = (u16*)d_ws;
  u16* xb    = ws;                             // 4096*768
  u16* wqkvT = xb    + 4096 * 768;             // 2304*768
  u16* woT   = wqkvT + 2304 * 768;             // 768*768
  u16* qb    = woT   + 768 * 768;              // 24*2048*64
  u16* kb    = qb    + 24 * 2048 * 64;
  u16* vtb   = kb    + 24 * 2048 * 64;         // V^T [24][64][2048]
  u16* aout  = vtb   + 24 * 2048 * 64;         // 4096*768

  prep<<<5376, 256, 0, stream>>>(x, xb, Wqkv, wqkvT, Wo, woT);

  gemm_qkv<<<dim3(6, 32, 3), 256, 0, stream>>>(xb, wqkvT, qb, kb, vtb, sl);

  attn_out<<<768, 256, 0, stream>>>(qb, kb, vtb, aout, woT, (float*)d_out);
}

// Round 16
// 85.597 us; speedup vs baseline: 2.7973x; 2.7973x over previous
//
#include <hip/hip_runtime.h>

typedef unsigned short u16;
typedef unsigned int   u32;
typedef __bf16  bf16x8 __attribute__((ext_vector_type(8)));
typedef float   f32x4  __attribute__((ext_vector_type(4)));
typedef u16     u16x8  __attribute__((ext_vector_type(8)));
typedef u16     u16x4  __attribute__((ext_vector_type(4)));
typedef u32     u32x2  __attribute__((ext_vector_type(2)));

#define MFMA16(a, b, c) __builtin_amdgcn_mfma_f32_16x16x32_bf16((a), (b), (c), 0, 0, 0)

// async global->LDS, 16B per lane (dest must be wave-uniform base + lane*16)
#define GLOAD16(gsrc, ldst)                                                     \
  __builtin_amdgcn_global_load_lds(                                             \
      (__attribute__((address_space(1))) void*)(gsrc),                          \
      (__attribute__((address_space(3))) void*)(ldst), 16, 0, 0)

__device__ __forceinline__ u16 f2bf(float f) {
  union { float f; unsigned u; } v; v.f = f;
  unsigned r = v.u + 0x7FFFu + ((v.u >> 16) & 1u);   // RNE
  return (u16)(r >> 16);
}
__device__ __forceinline__ float bf2f(u16 u) {
  union { unsigned u; float f; } v; v.u = ((unsigned)u) << 16; return v.f;
}
// pack two f32 -> two bf16 in one VALU op (lo -> bits 0..15)
__device__ __forceinline__ u32 cvtpk(float a, float b) {
  u32 r;
  asm("v_cvt_pk_bf16_f32 %0, %1, %2" : "=v"(r) : "v"(a), "v"(b));
  return r;
}

// --------------------------------------------------------------- fused prep --
// One kernel, three jobs by blockIdx range:
//   [0,3072)        : x fp32 -> xb bf16 (float4/u16x4 vectorized)
//   [3072,4800)     : Wqkv [768][2304] -> wqkvT [2304][768] bf16
//   [4800,5376)     : Wo   [768][768]  -> woT   [768][768]  bf16
__global__ __launch_bounds__(256) void prep(const float* __restrict__ x,
                                            u16* __restrict__ xb,
                                            const float* __restrict__ Wqkv,
                                            u16* __restrict__ wqkvT,
                                            const float* __restrict__ Wo,
                                            u16* __restrict__ woT) {
  __shared__ u16 tile[32][33];
  const int bx = blockIdx.x;
  if (bx < 3072) {                              // ---- f2bf on x
    int i = bx * 256 + threadIdx.x;             // n4 = 786432 = 3072*256
    const float4 v = reinterpret_cast<const float4*>(x)[i];
    u16x4 o; o.x = f2bf(v.x); o.y = f2bf(v.y); o.z = f2bf(v.z); o.w = f2bf(v.w);
    reinterpret_cast<u16x4*>(xb)[i] = o;
    return;
  }
  const float* in; u16* out; int R, C, c0, r0;
  if (bx < 4800) {                              // ---- transpose Wqkv
    const int i = bx - 3072;                    // 72 x 24 tiles
    in = Wqkv; out = wqkvT; R = 768; C = 2304;
    c0 = (i % 72) * 32; r0 = (i / 72) * 32;
  } else {                                      // ---- transpose Wo
    const int i = bx - 4800;                    // 24 x 24 tiles
    in = Wo; out = woT; R = 768; C = 768;
    c0 = (i % 24) * 32; r0 = (i / 24) * 32;
  }
  int tx = threadIdx.x & 31, ty = threadIdx.x >> 5;   // 8 rows per pass
  #pragma unroll
  for (int i = ty; i < 32; i += 8)
    tile[i][tx] = f2bf(in[(size_t)(r0 + i) * C + (c0 + tx)]);
  __syncthreads();
  #pragma unroll
  for (int i = ty; i < 32; i += 8)
    out[(size_t)(c0 + i) * R + (r0 + tx)] = tile[tx][i];
}

// ------------------------------------------------- fused QKV GEMM + RoPE ----
// A = xb [4096][768] bf16, Bt = wqkvT [2304][768] bf16.
// blockIdx.z = type (0=Q,1=K,2=V). 128x128 tile, BK=64, SINGLE-buffered
// (32KB LDS -> 5 blocks/CU; R10's 64KB dbuf cut residency to 2/CU and
// regressed 2x -- m132 mechanism). Both-sides XOR swizzle: bank-conflict
// count measured ZERO. R12 (64x128 retile), R13 (XCD panel swizzle), and
// R15 (persistent fusion with bt64) all regressed -- this is the verified
// best configuration (85.7us pipeline, reproduced twice).
// Epilogue: Q/K -> RoPE in fp32 -> q/k [bh][t][64] (Q pre-scaled by
// 0.125*log2e); V -> vt [bh][d][t].
__global__ __launch_bounds__(256) void gemm_qkv(const u16* __restrict__ A,
                                                const u16* __restrict__ Bt,
                                                u16* __restrict__ q,
                                                u16* __restrict__ k,
                                                u16* __restrict__ vt,
                                                const int* __restrict__ seq_len) {
  __shared__ u16 As[128 * 64];
  __shared__ u16 Bs[128 * 64];
  const int tid = threadIdx.x;
  const int lane = tid & 63;
  const int w  = tid >> 6;
  const int wr = w >> 1, wc = w & 1;           // 2x2 waves, each 64x64 out
  const int lo = lane & 15, g = lane >> 4;
  const int type = blockIdx.z;                 // 0=q 1=k 2=v
  const int bxl  = blockIdx.x;                 // 0..5
  const int m0 = blockIdx.y * 128;
  const int n0 = type * 768 + bxl * 128;
  const int K = 768;

  f32x4 acc[4][4] = {};
  for (int kt = 0; kt < 12; ++kt) {
    __syncthreads();
    #pragma unroll
    for (int i = 0; i < 4; ++i) {
      int idx = i * 256 + tid;                 // 1024 chunks of 16B per matrix
      int row = idx >> 3, sc = idx & 7;
      const int col = ((sc ^ (row & 7)) * 8);  // pre-swizzled source
      GLOAD16(&A [(size_t)(m0 + row) * K + kt * 64 + col], &As[idx * 8]);
      GLOAD16(&Bt[(size_t)(n0 + row) * K + kt * 64 + col], &Bs[idx * 8]);
    }
    __syncthreads();

    #pragma unroll
    for (int kk = 0; kk < 2; ++kk) {
      bf16x8 af[4], bfr[4];
      #pragma unroll
      for (int mi = 0; mi < 4; ++mi)
        af[mi] = *(const bf16x8*)&As[(wr * 64 + mi * 16 + lo) * 64 +
                                     (((kk * 4 + g) ^ (lo & 7)) * 8)];
      #pragma unroll
      for (int ni = 0; ni < 4; ++ni)
        bfr[ni] = *(const bf16x8*)&Bs[(wc * 64 + ni * 16 + lo) * 64 +
                                      (((kk * 4 + g) ^ (lo & 7)) * 8)];
      #pragma unroll
      for (int mi = 0; mi < 4; ++mi)
        #pragma unroll
        for (int ni = 0; ni < 4; ++ni)
          acc[mi][ni] = MFMA16(af[mi], bfr[ni], acc[mi][ni]);
    }
  }

  // epilogue: D layout col=lane&15 (within 16), row=(lane>>4)*4+r
  const int hh = bxl * 2 + wc;                 // head 0..11
  const int bb = m0 >> 11;                     // batch (128 | 2048)
  const int tbase = (m0 & 2047) + wr * 64;     // local t base for this wave

  if (type == 2) {                             // V -> vt [bh][d][t]
    #pragma unroll
    for (int ni = 0; ni < 4; ++ni) {
      const int d = ni * 16 + lo;
      u16* dst = &vt[(((size_t)bb * 12 + hh) * 64 + d) * 2048];
      #pragma unroll
      for (int mi = 0; mi < 4; ++mi) {
        const int tl = tbase + mi * 16 + g * 4;
        u16x4 o;
        #pragma unroll
        for (int r = 0; r < 4; ++r) o[r] = f2bf(acc[mi][ni][r]);
        *(u16x4*)&dst[tl] = o;
      }
    }
  } else {                                     // Q/K -> RoPE -> [bh][t][64]
    const float QS = 0.18033688011112042f;     // 0.125 * log2(e)
    const int off = seq_len[0];
    const float invf0 = __expf(-(float)lo        * 0.28782313662425572f);
    const float invf1 = __expf(-(float)(lo + 16) * 0.28782313662425572f);
    u16* base = &((type == 0) ? q : k)[((size_t)bb * 12 + hh) * 2048 * 64];
    #pragma unroll
    for (int mi = 0; mi < 4; ++mi)
      #pragma unroll
      for (int r = 0; r < 4; ++r) {
        const int tl = tbase + mi * 16 + g * 4 + r;
        const float pos = (float)(tl + off);
        float s0, c0, s1, c1;
        __sincosf(pos * invf0, &s0, &c0);
        __sincosf(pos * invf1, &s1, &c1);
        const float x1a = acc[mi][0][r], x2a = acc[mi][2][r];
        const float x1b = acc[mi][1][r], x2b = acc[mi][3][r];
        float o0 = x1a * c0 - x2a * s0, o2 = x2a * c0 + x1a * s0;
        float o1 = x1b * c1 - x2b * s1, o3 = x2b * c1 + x1b * s1;
        if (type == 0) { o0 *= QS; o1 *= QS; o2 *= QS; o3 *= QS; }
        u16* p = &base[(size_t)tl * 64];
        p[lo]      = f2bf(o0);
        p[lo + 16] = f2bf(o1);
        p[lo + 32] = f2bf(o2);
        p[lo + 48] = f2bf(o3);
      }
  }
}

// ---------------------------------------------------------------- out GEMM --
// C[M][N] = A[M][K] * Bt[N][K]^T, fp32 out.  64x128 tile, BK=64, DOUBLE-
// buffered (48KB -> 3 blocks/CU capacity; grid 384 = 1.5/CU is GRID-limited
// so the dbuf LDS is free -- R11 A/B: -1us vs single). XOR swizzle.
__global__ __launch_bounds__(256) void gemm_bt64(const u16* __restrict__ A,
                                                 const u16* __restrict__ Bt,
                                                 float* __restrict__ C,
                                                 int M, int N, int K) {
  __shared__ u16 As[2][64 * 64];
  __shared__ u16 Bs[2][128 * 64];
  const int tid = threadIdx.x;
  const int lane = tid & 63;
  const int w  = tid >> 6;
  const int wr = w >> 1, wc = w & 1;           // 2x2 waves, each 32x64 out
  const int lo = lane & 15, g = lane >> 4;
  const int m0 = blockIdx.y * 64, n0 = blockIdx.x * 128;

  auto stage = [&](int bu, int kt_) __attribute__((always_inline)) {
    #pragma unroll
    for (int i = 0; i < 2; ++i) {               // A: 512 chunks, 2/thread
      int idx = i * 256 + tid;
      int row = idx >> 3, sc = idx & 7;
      GLOAD16(&A[(size_t)(m0 + row) * K + kt_ * 64 + ((sc ^ (row & 7)) * 8)],
              &As[bu][idx * 8]);
    }
    #pragma unroll
    for (int i = 0; i < 4; ++i) {               // B: 1024 chunks, 4/thread
      int idx = i * 256 + tid;
      int row = idx >> 3, sc = idx & 7;
      GLOAD16(&Bt[(size_t)(n0 + row) * K + kt_ * 64 + ((sc ^ (row & 7)) * 8)],
              &Bs[bu][idx * 8]);
    }
  };

  f32x4 acc[2][4] = {};
  const int nk = K >> 6;
  stage(0, 0);
  __syncthreads();
  for (int kt = 0; kt < nk; ++kt) {
    const int cur = kt & 1;
    if (kt + 1 < nk) stage(cur ^ 1, kt + 1);    // prefetch next tile

    #pragma unroll
    for (int kk = 0; kk < 2; ++kk) {
      bf16x8 af[2], bfr[4];
      #pragma unroll
      for (int mi = 0; mi < 2; ++mi)
        af[mi] = *(const bf16x8*)&As[cur][(wr * 32 + mi * 16 + lo) * 64 +
                                          (((kk * 4 + g) ^ (lo & 7)) * 8)];
      #pragma unroll
      for (int ni = 0; ni < 4; ++ni)
        bfr[ni] = *(const bf16x8*)&Bs[cur][(wc * 64 + ni * 16 + lo) * 64 +
                                           (((kk * 4 + g) ^ (lo & 7)) * 8)];
      #pragma unroll
      for (int mi = 0; mi < 2; ++mi)
        #pragma unroll
        for (int ni = 0; ni < 4; ++ni)
          acc[mi][ni] = MFMA16(af[mi], bfr[ni], acc[mi][ni]);
    }
    __syncthreads();                            // drains prefetch after compute
  }

  #pragma unroll
  for (int mi = 0; mi < 2; ++mi)
    #pragma unroll
    for (int ni = 0; ni < 4; ++ni)
      #pragma unroll
      for (int r = 0; r < 4; ++r) {
        int row = m0 + wr * 32 + mi * 16 + g * 4 + r;
        int col = n0 + wc * 64 + ni * 16 + lo;
        C[(size_t)row * N + col] = acc[mi][ni][r];
      }
}

// ---------------------------------------------------------------- flash attn -
// v14 (fixed point; verified best 44.5us, reproduced across 3 runs). 4 waves
// / 256 thr / 64q block, grid 768 = ALL jobs co-resident (LDS 42KB -> 3
// blocks/CU). Fully static 1:1 block->job mapping; permutation
// anti-correlates job weights per CU. Ten structural variants (barriers,
// occupancy, counted vmcnt, no-LDS global-direct, split-kv, fusion) all
// returned ~45us or worse: latency-bound fixed point.
__global__ __launch_bounds__(256, 3) void fattn(const u16* __restrict__ Q,
                                                const u16* __restrict__ K,
                                                const u16* __restrict__ Vt,
                                                u16* __restrict__ O) {
  __shared__ u16 Ks[2][64 * 64];                // [kv][d-slots], swizzled
  __shared__ u16 Vs[2][64 * 64];                // [d][kv-slots], swizzled
  __shared__ __align__(16) u32 Ps[4][16 * 36];  // per-wave P; row stride 36 dw
  const int tid = threadIdx.x;
  const int w = tid >> 6, l = tid & 63;
  const int lo = l & 15, g = l >> 4;
  u32* myP = &Ps[w][lo * 36];                   // lane's own q-row

  // staging indices: 512 x 16B chunks per matrix, 2 per thread
  const int i0 = tid, i1 = 256 + tid;
  const int r0 = i0 >> 3, s0 = i0 & 7;
  const int r1 = i1 >> 3, s1 = i1 & 7;
  const size_t kg0 = (size_t)r0 * 64   + ((s0 ^ (r0 & 7)) * 8);
  const size_t vg0 = (size_t)r0 * 2048 + ((s0 ^ (r0 & 7)) * 8);
  const size_t kg1 = (size_t)r1 * 64   + ((s1 ^ (r1 & 7)) * 8);
  const size_t vg1 = (size_t)r1 * 2048 + ((s1 ^ (r1 & 7)) * 8);

  // static block -> job-rank permutation (768 jobs, rank 0 = heaviest)
  const int bx = blockIdx.x;
  int rk;
  if (bx < 256)      rk = bx;                   // heavy: nkv 32..22
  else if (bx < 512) rk = 1023 - bx;            // light: nkv 1..10 (pairs w/ heavy)
  else { const int c = bx - 512;                // middle: nkv 11..21, interleaved
         rk = (c & 1) ? 511 - (c >> 1) : 256 + (c >> 1); }

  // rank -> (bh, qg): qg = 31 - rk/24 (heavy-first); bh bijective per band,
  // low 3 bits pick the bh triple => XCD-pinned.
  const int qg  = 31 - rk / 24;
  const int bh  = (rk & 7) * 3 + ((rk >> 3) % 3);
  const int nkv = qg + 1;
  const int q0  = qg * 64 + w * 16;             // wave's first q row
  const u16* Qb = Q  + (size_t)bh * 2048 * 64;
  const u16* Kb = K  + (size_t)bh * 2048 * 64;
  const u16* Vb = Vt + (size_t)bh * 64 * 2048;
  const int b = bh / 12, h = bh - b * 12;

  const bf16x8 qf0 = *(const bf16x8*)&Qb[(size_t)(q0 + lo) * 64 + g * 8];
  const bf16x8 qf1 = *(const bf16x8*)&Qb[(size_t)(q0 + lo) * 64 + 32 + g * 8];

  f32x4 acc[4] = {};                            // acc[dt][r]: O^T[16dt+4g+r][q0+lo]
  float m_run = -1e30f, l_run = 0.f;            // l_run is LANE-PARTIAL

  // one flash step over LDS buffer cur. diag folds at compile time.
  auto step = [&](int cur, bool diag) __attribute__((always_inline)) {
    bf16x8 kf[8];
    #pragma unroll
    for (int ct = 0; ct < 4; ++ct) {
      const int base = (ct * 16 + lo) * 64;
      kf[ct * 2]     = *(const bf16x8*)&Ks[cur][base + ((g ^ (lo & 7)) * 8)];
      kf[ct * 2 + 1] = *(const bf16x8*)&Ks[cur][base + (((4 + g) ^ (lo & 7)) * 8)];
    }
    bf16x8 vf[8];                               // early: overlaps softmax
    #pragma unroll
    for (int ss = 0; ss < 2; ++ss)
      #pragma unroll
      for (int dt = 0; dt < 4; ++dt) {
        const int row = dt * 16 + lo;
        vf[ss * 4 + dt] = *(const bf16x8*)&Vs[cur][row * 64 + (((ss * 4 + g) ^ (lo & 7)) * 8)];
      }

    f32x4 s[4];
    __builtin_amdgcn_s_setprio(1);
    #pragma unroll
    for (int ct = 0; ct < 4; ++ct) {
      f32x4 t = {};
      t = MFMA16(kf[ct * 2], qf0, t);
      t = MFMA16(kf[ct * 2 + 1], qf1, t);
      s[ct] = t;
    }
    __builtin_amdgcn_s_setprio(0);

    if (diag) {                                 // tiles ct<w full, ct==w tri, ct>w off
      #pragma unroll
      for (int ct = 0; ct < 4; ++ct) {
        if (ct > w) s[ct] = (f32x4){-1e30f, -1e30f, -1e30f, -1e30f};
        else if (ct == w) {
          #pragma unroll
          for (int r = 0; r < 4; ++r)
            if (g * 4 + r > lo) s[ct][r] = -1e30f;
        }
      }
    }

    float pm = s[0][0];                         // lane-local max only
    #pragma unroll
    for (int ct = 0; ct < 4; ++ct)
      #pragma unroll
      for (int r = 0; r < 4; ++r) pm = fmaxf(pm, s[ct][r]);
    if (!__all(pm - m_run <= 12.0f)) {          // rare: row max + rescale
      float pr = fmaxf(pm, __shfl_xor(pm, 16));
      pr = fmaxf(pr, __shfl_xor(pr, 32));
      const float mnew = fmaxf(m_run, pr);
      const float corr = exp2f(m_run - mnew);
      l_run *= corr;
      #pragma unroll
      for (int dt = 0; dt < 4; ++dt)
        #pragma unroll
        for (int r = 0; r < 4; ++r) acc[dt][r] *= corr;
      m_run = mnew;
    }
    float p[4][4];
    float rs = 0.f;
    #pragma unroll
    for (int ct = 0; ct < 4; ++ct)
      #pragma unroll
      for (int r = 0; r < 4; ++r) {
        float pv = exp2f(s[ct][r] - m_run);     // scores already in log2 domain
        p[ct][r] = pv; rs += pv;
      }
    l_run += rs;

    #pragma unroll
    for (int ct = 0; ct < 4; ++ct) {            // P -> per-wave LDS (cvt_pk)
      u32x2 pk;
      pk.x = cvtpk(p[ct][0], p[ct][1]);
      pk.y = cvtpk(p[ct][2], p[ct][3]);
      *(u32x2*)&myP[ct * 8 + g * 2] = pk;
    }

    __builtin_amdgcn_s_setprio(1);
    #pragma unroll
    for (int ss = 0; ss < 2; ++ss) {
      const bf16x8 pf = *(const bf16x8*)&myP[ss * 16 + g * 4];
      #pragma unroll
      for (int dt = 0; dt < 4; ++dt)
        acc[dt] = MFMA16(vf[ss * 4 + dt], pf, acc[dt]);
    }
    __builtin_amdgcn_s_setprio(0);
  };

  // incremental staging pointers (tile stride: K 64*64, Vt 64 u16)
  const u16 *kp0 = Kb + kg0, *kp1 = Kb + kg1;
  const u16 *vp0 = Vb + vg0, *vp1 = Vb + vg1;

  // prologue: stage tile 0 into buffer 0
  GLOAD16(kp0, &Ks[0][i0 * 8]);
  GLOAD16(kp1, &Ks[0][i1 * 8]);
  GLOAD16(vp0, &Vs[0][i0 * 8]);
  GLOAD16(vp1, &Vs[0][i1 * 8]);
  __syncthreads();

  for (int it = 0; it < nkv - 1; ++it) {        // maskless main loop
    const int cur = it & 1;
    kp0 += 4096; kp1 += 4096; vp0 += 64; vp1 += 64;
    GLOAD16(kp0, &Ks[cur ^ 1][i0 * 8]);
    GLOAD16(kp1, &Ks[cur ^ 1][i1 * 8]);
    GLOAD16(vp0, &Vs[cur ^ 1][i0 * 8]);
    GLOAD16(vp1, &Vs[cur ^ 1][i1 * 8]);
    step(cur, false);
    __syncthreads();
  }
  step((nkv - 1) & 1, true);                    // single peeled diag step

  float lt = l_run;                             // row reduce, once
  lt += __shfl_xor(lt, 16);
  lt += __shfl_xor(lt, 32);
  const float inv = 1.f / lt;
  #pragma unroll
  for (int dt = 0; dt < 4; ++dt) {
    u16x4 o;
    #pragma unroll
    for (int r = 0; r < 4; ++r) o[r] = f2bf(acc[dt][r] * inv);
    *(u16x4*)&O[(size_t)(b * 2048 + q0 + lo) * 768 + h * 64 + dt * 16 + g * 4] = o;
  }
}

// ---------------------------------------------------------------- launch ----
extern "C" void kernel_launch(void* const* d_in, const int* in_sizes, int n_in,
                              void* d_out, int out_size, void* d_ws, size_t ws_size,
                              hipStream_t stream) {
  const float* x    = (const float*)d_in[0];   // [2,2048,768]
  const float* Wqkv = (const float*)d_in[1];   // [768,2304]
  const float* Wo   = (const float*)d_in[2];   // [768,768]
  const int*   sl   = (const int*)d_in[3];

  u16* ws    = (u16*)d_ws;
  u16* xb    = ws;                             // 4096*768
  u16* wqkvT = xb    + 4096 * 768;             // 2304*768
  u16* woT   = wqkvT + 2304 * 768;             // 768*768
  u16* qb    = woT   + 768 * 768;              // 24*2048*64
  u16* kb    = qb    + 24 * 2048 * 64;
  u16* vtb   = kb    + 24 * 2048 * 64;         // V^T [24][64][2048]
  u16* aout  = vtb   + 24 * 2048 * 64;         // 4096*768

  prep<<<5376, 256, 0, stream>>>(x, xb, Wqkv, wqkvT, Wo, woT);

  gemm_qkv<<<dim3(6, 32, 3), 256, 0, stream>>>(xb, wqkvT, qb, kb, vtb, sl);

  fattn<<<768, 256, 0, stream>>>(qb, kb, vtb, aout);

  gemm_bt64<<<dim3(6, 64), 256, 0, stream>>>(aout, woT, (float*)d_out,
                                             4096, 768, 768);
}